// Round 6
// baseline (190.346 us; speedup 1.0000x reference)
//
#include <hip/hip_runtime.h>
#include <stdint.h>

#define N_BATCH 32
#define B_OBJ   36
#define D_DIM   2048
#define Q_DIM   1024

typedef __bf16 bf16x8  __attribute__((ext_vector_type(8)));
typedef float  f32x4   __attribute__((ext_vector_type(4)));
typedef float  f32x16  __attribute__((ext_vector_type(16)));

__device__ __forceinline__ uint16_t f2bf(float f) {
    uint32_t u = __builtin_bit_cast(uint32_t, f);
    uint32_t r = (u + 0x7FFFu + ((u >> 16) & 1u)) >> 16;   // RNE
    return (uint16_t)r;
}

__device__ __forceinline__ void gld_lds16(const void* g, void* l) {
    __builtin_amdgcn_global_load_lds(
        (const __attribute__((address_space(1))) uint32_t*)g,
        (__attribute__((address_space(3))) uint32_t*)l, 16, 0, 0);
}

// ---- transpose + fp32->bf16 for W1, W2 (2048x2048 each) ----
__global__ __launch_bounds__(256) void transpose_all(
    const float* __restrict__ W1, const float* __restrict__ W2,
    uint16_t* __restrict__ W1t, uint16_t* __restrict__ W2t) {
    __shared__ float tile[64][65];
    int gy = blockIdx.y;
    const float* W; uint16_t* Wt; int k0;
    if (gy < 32) { W = W1; Wt = W1t; k0 = gy * 64; }
    else         { W = W2; Wt = W2t; k0 = (gy - 32) * 64; }
    int n0 = blockIdx.x * 64;
    int t = threadIdx.x;
    {
        int r = t >> 4, c = (t & 15) * 4;
#pragma unroll
        for (int p = 0; p < 4; ++p)
            *(float4*)&tile[r + p * 16][c] =
                *(const float4*)&W[(size_t)(k0 + r + p * 16) * 2048 + n0 + c];
    }
    __syncthreads();
    {
        int n = t >> 2, kb = (t & 3) * 16;
#pragma unroll
        for (int g4 = 0; g4 < 4; ++g4) {
            int k = kb + g4 * 4;
            ushort4 o;
            o.x = f2bf(tile[k][n]);     o.y = f2bf(tile[k + 1][n]);
            o.z = f2bf(tile[k + 2][n]); o.w = f2bf(tile[k + 3][n]);
            *(ushort4*)&Wt[(size_t)(n0 + n) * 2048 + k0 + k] = o;
        }
    }
}

// ---- q-path fp32 split-K: qpart[kz][n][e] ----
__global__ __launch_bounds__(256) void qe_f32(
    const float* __restrict__ q, const float* __restrict__ W3,
    float* __restrict__ qpart) {
    __shared__ float qs[128][32];     // [k][n]
    int t = threadIdx.x;
    int e0 = blockIdx.x * 64;
    int kbase = blockIdx.y * 128;
    {
        int nn = t >> 3, kg = (t & 7) * 16;
#pragma unroll
        for (int p = 0; p < 4; ++p) {
            float4 f = *(const float4*)&q[(size_t)nn * Q_DIM + kbase + kg + p * 4];
            qs[kg + p * 4 + 0][nn] = f.x; qs[kg + p * 4 + 1][nn] = f.y;
            qs[kg + p * 4 + 2][nn] = f.z; qs[kg + p * 4 + 3][nn] = f.w;
        }
    }
    __syncthreads();
    int n = t >> 3, e8 = (t & 7) * 8;
    float acc[8] = {};
#pragma unroll 4
    for (int k = 0; k < 128; ++k) {
        float qv = qs[k][n];
        float4 wa = *(const float4*)&W3[(size_t)(kbase + k) * D_DIM + e0 + e8];
        float4 wb = *(const float4*)&W3[(size_t)(kbase + k) * D_DIM + e0 + e8 + 4];
        acc[0] += qv * wa.x; acc[1] += qv * wa.y; acc[2] += qv * wa.z; acc[3] += qv * wa.w;
        acc[4] += qv * wb.x; acc[5] += qv * wb.y; acc[6] += qv * wb.z; acc[7] += qv * wb.w;
    }
    float* dst = qpart + (size_t)blockIdx.y * 32 * D_DIM + (size_t)n * D_DIM + e0 + e8;
    *(float4*)dst = *(float4*)&acc[0];
    *(float4*)(dst + 4) = *(float4*)&acc[4];
}

// ---- fused: qe = relu(sum_z qpart + b3); u[n,i,:] = bf16(v[n,i,:]*qe) ----
__global__ __launch_bounds__(256) void qe_makeu(
    const float* __restrict__ qpart, const float* __restrict__ b3,
    const float* __restrict__ v, uint16_t* __restrict__ u) {
    int n = blockIdx.y;
    int c4 = blockIdx.x * 256 + threadIdx.x;
    const float4* p = (const float4*)qpart;
    size_t base = (size_t)n * 512 + c4;
    float4 s = p[base];
#pragma unroll
    for (int z = 1; z < 8; ++z) {
        float4 sz = p[(size_t)z * 16384 + base];
        s.x += sz.x; s.y += sz.y; s.z += sz.z; s.w += sz.w;
    }
    float4 b = ((const float4*)b3)[c4];
    float4 qe;
    qe.x = fmaxf(s.x + b.x, 0.f); qe.y = fmaxf(s.y + b.y, 0.f);
    qe.z = fmaxf(s.z + b.z, 0.f); qe.w = fmaxf(s.w + b.w, 0.f);
    const float4* v4 = (const float4*)v + (size_t)n * B_OBJ * 512 + c4;
    ushort4* u4 = (ushort4*)u + (size_t)n * B_OBJ * 512 + c4;
#pragma unroll 4
    for (int i = 0; i < B_OBJ; ++i) {
        float4 vv = v4[(size_t)i * 512];
        ushort4 o;
        o.x = f2bf(vv.x * qe.x); o.y = f2bf(vv.y * qe.y);
        o.z = f2bf(vv.z * qe.z); o.w = f2bf(vv.w * qe.w);
        u4[(size_t)i * 512] = o;
    }
}

// ---- fused GEMM: tile 96(72 real)x64, 2 waves, 32x32x16 MFMA, dbuf LDS ----
// mode 0: pairsum epilogue -> X bf16.  mode 1: relu(+bias) -> out f32.
// LDS elems (uint16): As[2][2][96][32] = 12288, Bs[2][2][64][32] = 8192 -> 40 KiB
// epilogue mode 0 reuses LDS as yt[72][68] f32 (19.6 KiB).
__global__ __launch_bounds__(128) void gemm_fused(
    const uint16_t* __restrict__ A,    // (1152+pad) x 2048 bf16
    const uint16_t* __restrict__ Bt,   // 2048 x 2048 bf16 (n-major)
    const float* __restrict__ bias,
    void* __restrict__ Cv,
    int mode) {
    __shared__ __align__(16) uint16_t sm[20480];
    float* yt = (float*)sm;

    int t = threadIdx.x, lane = t & 63, wave = t >> 6;
    int l31 = lane & 31, khalf = lane >> 5;          // MFMA lane decomposition
    int bg = blockIdx.y;                             // 2-batch group: rows 72*bg..+71 (+24 pad)
    int n0 = blockIdx.x * 64;
    const uint16_t* Ab = A + (size_t)bg * 72 * D_DIM;

    // 20 staging regions of 1 KiB (16 rows x 32 k): 0..11 = A[h=r/6][g=r%6],
    // 12..19 = B[h=rb>>2][g=rb&3]. wave w stages regions w*10..w*10+9.
    const uint16_t* gp[10]; uint16_t* lp[10]; int bufstep[10];
    {
        int row16 = lane >> 2, kin = (lane & 3) * 8;
#pragma unroll
        for (int c = 0; c < 10; ++c) {
            int r = wave * 10 + c;
            if (r < 12) {
                int h = r / 6, g = r % 6;
                gp[c] = Ab + (size_t)(g * 16 + row16) * D_DIM + h * 32 + kin;
                lp[c] = sm + h * 3072 + g * 512;
                bufstep[c] = 6144;
            } else {
                int rb = r - 12, h = rb >> 2, g = rb & 3;
                gp[c] = Bt + (size_t)(n0 + g * 16 + row16) * D_DIM + h * 32 + kin;
                lp[c] = sm + 12288 + h * 2048 + g * 512;
                bufstep[c] = 4096;
            }
        }
    }

    f32x16 acc[3] = {};

    // prologue: fill buffer 0
#pragma unroll
    for (int c = 0; c < 10; ++c) gld_lds16(gp[c], lp[c]);

    for (int it = 0; it < 32; ++it) {
        int buf = it & 1;
        __syncthreads();                 // waits own vmcnt(0) first -> buf ready
        if (it < 31) {
            int nxt = buf ^ 1;
#pragma unroll
            for (int c = 0; c < 10; ++c)
                gld_lds16(gp[c] + (size_t)(it + 1) * 64, lp[c] + nxt * bufstep[c]);
        }
#pragma unroll
        for (int s = 0; s < 4; ++s) {    // k-segs of 16 within BK=64
            int h = s >> 1, kin = (s & 1) * 16 + khalf * 8;
            bf16x8 bfr = *(const bf16x8*)(sm + 12288 + buf * 4096 + h * 2048 +
                                          (wave * 32 + l31) * 32 + kin);
#pragma unroll
            for (int mt = 0; mt < 3; ++mt) {
                bf16x8 af = *(const bf16x8*)(sm + buf * 6144 + h * 3072 +
                                             (mt * 32 + l31) * 32 + kin);
                acc[mt] = __builtin_amdgcn_mfma_f32_32x32x16_bf16(af, bfr, acc[mt], 0, 0, 0);
            }
        }
    }

    // C/D layout (verified m74/m101): col = lane&31, row = (reg&3)+8*(reg>>2)+4*(lane>>5)
    if (mode == 0) {
        uint16_t* X = (uint16_t*)Cv;
        __syncthreads();
#pragma unroll
        for (int mt = 0; mt < 3; ++mt)
#pragma unroll
            for (int reg = 0; reg < 16; ++reg) {
                int row = mt * 32 + (reg & 3) + 8 * (reg >> 2) + 4 * khalf;
                if (row < 72) yt[row * 68 + wave * 32 + l31] = acc[mt][reg];
            }
        __syncthreads();
        int col = t & 63, half = t >> 6;             // half = batch within group
        float b = bias[n0 + col];
        float z[36];
#pragma unroll
        for (int j = 0; j < 36; ++j) z[j] = yt[(half * 36 + j) * 68 + col];
        uint16_t* xb = X + (size_t)(bg * 72 + half * 36) * D_DIM + n0 + col;
#pragma unroll
        for (int i = 0; i < 36; ++i) {
            float zi = z[i] + b;
            float ssum = 0.f;
#pragma unroll
            for (int j = 0; j < 36; ++j) ssum += fmaxf(zi + z[j], 0.f);
            xb[(size_t)i * D_DIM] = f2bf(ssum);
        }
    } else {
        float* O = (float*)Cv;
        int col = n0 + wave * 32 + l31;
        float b = bias[col];
#pragma unroll
        for (int mt = 0; mt < 3; ++mt)
#pragma unroll
            for (int reg = 0; reg < 16; ++reg) {
                int row = mt * 32 + (reg & 3) + 8 * (reg >> 2) + 4 * khalf;
                if (row < 72)
                    O[(size_t)(bg * 72 + row) * D_DIM + col] =
                        fmaxf(acc[mt][reg] + b, 0.f);
            }
    }
}

extern "C" void kernel_launch(void* const* d_in, const int* in_sizes, int n_in,
                              void* d_out, int out_size, void* d_ws, size_t ws_size,
                              hipStream_t stream) {
    const float* v  = (const float*)d_in[0];
    const float* q  = (const float*)d_in[1];
    const float* W1 = (const float*)d_in[2];
    const float* b1 = (const float*)d_in[3];
    const float* W2 = (const float*)d_in[4];
    const float* b2 = (const float*)d_in[5];
    const float* W3 = (const float*)d_in[6];
    const float* b3 = (const float*)d_in[7];
    float* out = (float*)d_out;

    char* ws = (char*)d_ws;
    uint16_t* W1t   = (uint16_t*)(ws + 0);           //  8 MiB
    uint16_t* W2t   = (uint16_t*)(ws + 8388608);     //  8 MiB
    uint16_t* u     = (uint16_t*)(ws + 16777216);    //  4.5 MiB (+pad reads into qpart, safe)
    float*    qpart = (float*)   (ws + 21495808);    //  2 MiB
    uint16_t* x     = (uint16_t*)(ws + 23592960);    //  4.5 MiB (+96 KiB pad-read slack after)

    transpose_all<<<dim3(32, 64), 256, 0, stream>>>(W1, W2, W1t, W2t);

    qe_f32<<<dim3(32, 8), 256, 0, stream>>>(q, W3, qpart);
    qe_makeu<<<dim3(2, N_BATCH), 256, 0, stream>>>(qpart, b3, v, u);

    // GEMM1 + fused pairsum -> x (bf16)
    gemm_fused<<<dim3(32, 16), 128, 0, stream>>>(u, W1t, b1, x, 0);

    // GEMM2 + bias + relu -> out (f32)
    gemm_fused<<<dim3(32, 16), 128, 0, stream>>>(x, W2t, b2, out, 1);
}